// Round 1
// baseline (269.890 us; speedup 1.0000x reference)
//
#include <hip/hip_runtime.h>
#include <hip/hip_bf16.h>

typedef short short8 __attribute__((ext_vector_type(8)));
typedef float f32x4 __attribute__((ext_vector_type(4)));

#define M_TOT 16384   // B*S = 4*4096
#define NDIM  1024    // D = U = 1024
#define BM 128
#define BN 128
#define BK 32

static __device__ __forceinline__ unsigned short f2bf(float f) {
  unsigned int u = __builtin_bit_cast(unsigned int, f);
  unsigned int r = (u + 0x7fffu + ((u >> 16) & 1u)) >> 16;   // RN-even
  return (unsigned short)r;
}
static __device__ __forceinline__ float bf2f(unsigned short u) {
  return __builtin_bit_cast(float, ((unsigned int)u) << 16);
}

// ---------------- cast inputs fp32 -> bf16, vectorized ----------------
__global__ __launch_bounds__(256) void cast_in(const float* __restrict__ in,
                                               unsigned short* __restrict__ out,
                                               int n4) {
  int i = blockIdx.x * 256 + threadIdx.x;
  if (i >= n4) return;
  float4 v = reinterpret_cast<const float4*>(in)[i];
  ushort4 o;
  o.x = f2bf(v.x); o.y = f2bf(v.y); o.z = f2bf(v.z); o.w = f2bf(v.w);
  reinterpret_cast<ushort4*>(out)[i] = o;
}

// -------- transpose-cast weight fp32 [K=1024][N=1024] -> bf16 [N][K] --------
__global__ __launch_bounds__(256) void tcast(const float* __restrict__ src,
                                             unsigned short* __restrict__ dst) {
  __shared__ unsigned short tile[32][33];
  int bx = blockIdx.x * 32, by = blockIdx.y * 32;
  int x = threadIdx.x & 31, y = threadIdx.x >> 5;  // 32 x 8
#pragma unroll
  for (int i = 0; i < 32; i += 8)
    tile[y + i][x] = f2bf(src[(size_t)(by + y + i) * NDIM + bx + x]);
  __syncthreads();
#pragma unroll
  for (int i = 0; i < 32; i += 8)
    dst[(size_t)(bx + y + i) * NDIM + by + x] = tile[x][y + i];
}

// ---------------- bf16 MFMA GEMM, C = A[M][K] * Bt[N][K]^T ----------------
// MODE 0: Obf = bf16(relu(C+bias))        (h)
// MODE 1: Obf = bf16(sigmoid(C+bias))     (g)
// MODE 2: Of  = C+bias (fp32)             (s)
// MODE 3: Of  = (C+bias)*G + S (fp32)     (y)
template <int MODE>
__global__ __launch_bounds__(256) void gemm_bt(
    const unsigned short* __restrict__ A,
    const unsigned short* __restrict__ Bt,
    const float* __restrict__ bias,
    unsigned short* __restrict__ Obf,
    float* __restrict__ Of,
    const unsigned short* __restrict__ G,
    const float* __restrict__ S) {
  __shared__ __align__(16) unsigned short As[BM * BK];
  __shared__ __align__(16) unsigned short Bs[BN * BK];
  const int tid = threadIdx.x;
  const int lane = tid & 63, wave = tid >> 6;
  const int wm = wave >> 1, wn = wave & 1;
  const int m0 = blockIdx.x * BM, n0 = blockIdx.y * BN;

  f32x4 acc[4][4] = {};

  for (int k0 = 0; k0 < NDIM; k0 += BK) {
    // stage A,B tiles: 8KB each; per wave 2 chunks of 64 lanes x 16B
#pragma unroll
    for (int j = 0; j < 2; ++j) {
      int c = (wave * 2 + j) * 64 + lane;  // 16B-chunk id, 0..511
      int r = c >> 2;                      // row in tile
      int kb = (c & 3) << 3;               // k offset (shorts)
      const unsigned short* ga = A + (size_t)(m0 + r) * NDIM + k0 + kb;
      const unsigned short* gb = Bt + (size_t)(n0 + r) * NDIM + k0 + kb;
      __builtin_amdgcn_global_load_lds(
          (__attribute__((address_space(1))) void*)ga,
          (__attribute__((address_space(3))) void*)(As + (wave * 2 + j) * 512),
          16, 0, 0);
      __builtin_amdgcn_global_load_lds(
          (__attribute__((address_space(1))) void*)gb,
          (__attribute__((address_space(3))) void*)(Bs + (wave * 2 + j) * 512),
          16, 0, 0);
    }
    __syncthreads();

    short8 af[4], bfr[4];
#pragma unroll
    for (int i = 0; i < 4; ++i) {
      int ar = wm * 64 + i * 16 + (lane & 15);
      af[i] = *reinterpret_cast<const short8*>(&As[ar * BK + ((lane >> 4) << 3)]);
      int br = wn * 64 + i * 16 + (lane & 15);
      bfr[i] = *reinterpret_cast<const short8*>(&Bs[br * BK + ((lane >> 4) << 3)]);
    }
#pragma unroll
    for (int i = 0; i < 4; ++i)
#pragma unroll
      for (int j = 0; j < 4; ++j)
        acc[i][j] = __builtin_amdgcn_mfma_f32_16x16x32_bf16(af[i], bfr[j], acc[i][j], 0, 0, 0);
    __syncthreads();
  }

  // epilogue: C/D layout col = lane&15, row = (lane>>4)*4 + r  [m89]
  const int crow0 = m0 + wm * 64;
  const int ccol0 = n0 + wn * 64;
#pragma unroll
  for (int i = 0; i < 4; ++i) {
#pragma unroll
    for (int j = 0; j < 4; ++j) {
      int row = crow0 + i * 16 + ((lane >> 4) << 2);
      int col = ccol0 + j * 16 + (lane & 15);
      float bc = bias[col];
#pragma unroll
      for (int r = 0; r < 4; ++r) {
        float v = acc[i][j][r] + bc;
        size_t idx = (size_t)(row + r) * NDIM + col;
        if (MODE == 0) {
          Obf[idx] = f2bf(fmaxf(v, 0.f));
        } else if (MODE == 1) {
          Obf[idx] = f2bf(1.f / (1.f + __expf(-v)));
        } else if (MODE == 2) {
          Of[idx] = v;
        } else {
          Of[idx] = v * bf2f(G[idx]) + S[idx];
        }
      }
    }
  }
}

// ---------------- in-place LayerNorm over rows of 1024 fp32 ----------------
__global__ __launch_bounds__(256) void layernorm_inplace(
    float* __restrict__ Y, const float* __restrict__ gamma,
    const float* __restrict__ beta) {
  const int tid = threadIdx.x;
  float* y = Y + (size_t)blockIdx.x * NDIM;
  float4 v = reinterpret_cast<const float4*>(y)[tid];
  float s1 = v.x + v.y + v.z + v.w;
  float s2 = v.x * v.x + v.y * v.y + v.z * v.z + v.w * v.w;
#pragma unroll
  for (int o = 32; o > 0; o >>= 1) {
    s1 += __shfl_down(s1, o, 64);
    s2 += __shfl_down(s2, o, 64);
  }
  __shared__ float red[8];
  int wave = tid >> 6, lane = tid & 63;
  if (lane == 0) { red[wave] = s1; red[wave + 4] = s2; }
  __syncthreads();
  float S1 = red[0] + red[1] + red[2] + red[3];
  float S2 = red[4] + red[5] + red[6] + red[7];
  float mu = S1 * (1.f / NDIM);
  float var = S2 * (1.f / NDIM) - mu * mu;
  float inv = rsqrtf(var + 1e-3f);
  float4 gm = reinterpret_cast<const float4*>(gamma)[tid];
  float4 bt = reinterpret_cast<const float4*>(beta)[tid];
  float4 o;
  o.x = (v.x - mu) * inv * gm.x + bt.x;
  o.y = (v.y - mu) * inv * gm.y + bt.y;
  o.z = (v.z - mu) * inv * gm.z + bt.z;
  o.w = (v.w - mu) * inv * gm.w + bt.w;
  reinterpret_cast<float4*>(y)[tid] = o;
}

extern "C" void kernel_launch(void* const* d_in, const int* in_sizes, int n_in,
                              void* d_out, int out_size, void* d_ws, size_t ws_size,
                              hipStream_t stream) {
  const float* inp = (const float*)d_in[0];
  const float* w1 = (const float*)d_in[1];
  const float* b1 = (const float*)d_in[2];
  const float* w2 = (const float*)d_in[3];
  const float* b2 = (const float*)d_in[4];
  const float* wg = (const float*)d_in[5];
  const float* bg = (const float*)d_in[6];
  const float* wsk = (const float*)d_in[7];
  const float* bs = (const float*)d_in[8];
  const float* gamma = (const float*)d_in[9];
  const float* beta = (const float*)d_in[10];

  char* p = (char*)d_ws;
  const size_t act_bf16 = (size_t)M_TOT * NDIM * 2;
  const size_t act_f32 = (size_t)M_TOT * NDIM * 4;
  const size_t w_bf16 = (size_t)NDIM * NDIM * 2;
  unsigned short* Ain = (unsigned short*)p; p += act_bf16;
  unsigned short* H   = (unsigned short*)p; p += act_bf16;
  unsigned short* G   = (unsigned short*)p; p += act_bf16;
  float*          S   = (float*)p;          p += act_f32;
  unsigned short* W1t = (unsigned short*)p; p += w_bf16;
  unsigned short* W2t = (unsigned short*)p; p += w_bf16;
  unsigned short* Wgt = (unsigned short*)p; p += w_bf16;
  unsigned short* Wst = (unsigned short*)p; p += w_bf16;
  float* Y = (float*)d_out;

  cast_in<<<(M_TOT * NDIM / 4 + 255) / 256, 256, 0, stream>>>(inp, Ain, M_TOT * NDIM / 4);
  dim3 tg(32, 32);
  tcast<<<tg, 256, 0, stream>>>(w1, W1t);
  tcast<<<tg, 256, 0, stream>>>(w2, W2t);
  tcast<<<tg, 256, 0, stream>>>(wg, Wgt);
  tcast<<<tg, 256, 0, stream>>>(wsk, Wst);

  dim3 gg(M_TOT / BM, NDIM / BN);
  gemm_bt<0><<<gg, 256, 0, stream>>>(Ain, W1t, b1, H, nullptr, nullptr, nullptr);
  gemm_bt<1><<<gg, 256, 0, stream>>>(Ain, Wgt, bg, G, nullptr, nullptr, nullptr);
  gemm_bt<2><<<gg, 256, 0, stream>>>(Ain, Wst, bs, nullptr, S, nullptr, nullptr);
  gemm_bt<3><<<gg, 256, 0, stream>>>(H, W2t, b2, nullptr, Y, G, S);
  layernorm_inplace<<<M_TOT, 256, 0, stream>>>(Y, gamma, beta);
}

// Round 2
// 241.305 us; speedup vs baseline: 1.1185x; 1.1185x over previous
//
#include <hip/hip_runtime.h>
#include <hip/hip_bf16.h>

typedef short short8 __attribute__((ext_vector_type(8)));
typedef float f32x4 __attribute__((ext_vector_type(4)));

#define M_TOT 16384   // B*S = 4*4096
#define NDIM  1024    // D = U = 1024
#define BM 256
#define BN 256
#define BK 64
#define NT (NDIM / BK)   // 16 K-tiles

static __device__ __forceinline__ unsigned short f2bf(float f) {
  unsigned int u = __builtin_bit_cast(unsigned int, f);
  unsigned int r = (u + 0x7fffu + ((u >> 16) & 1u)) >> 16;   // RN-even
  return (unsigned short)r;
}
static __device__ __forceinline__ float bf2f(unsigned short u) {
  return __builtin_bit_cast(float, ((unsigned int)u) << 16);
}

// ---------------- cast inputs fp32 -> bf16, vectorized ----------------
__global__ __launch_bounds__(256) void cast_in(const float* __restrict__ in,
                                               unsigned short* __restrict__ out,
                                               int n4) {
  int i = blockIdx.x * 256 + threadIdx.x;
  if (i >= n4) return;
  float4 v = reinterpret_cast<const float4*>(in)[i];
  ushort4 o;
  o.x = f2bf(v.x); o.y = f2bf(v.y); o.z = f2bf(v.z); o.w = f2bf(v.w);
  reinterpret_cast<ushort4*>(out)[i] = o;
}

// -------- transpose-cast weight fp32 [K=1024][N=1024] -> bf16 [N][K] --------
__global__ __launch_bounds__(256) void tcast(const float* __restrict__ src,
                                             unsigned short* __restrict__ dst) {
  __shared__ unsigned short tile[32][33];
  int bx = blockIdx.x * 32, by = blockIdx.y * 32;
  int x = threadIdx.x & 31, y = threadIdx.x >> 5;  // 32 x 8
#pragma unroll
  for (int i = 0; i < 32; i += 8)
    tile[y + i][x] = f2bf(src[(size_t)(by + y + i) * NDIM + bx + x]);
  __syncthreads();
#pragma unroll
  for (int i = 0; i < 32; i += 8)
    dst[(size_t)(bx + y + i) * NDIM + by + x] = tile[x][y + i];
}

// ============ 256x256 / BK=64, 8-wave phase-split bf16 MFMA GEMM ============
// C = A[M][K] * Bt[N][K]^T, K = NDIM.
// MODE 0: Obf = bf16(relu(C+bias))        (h)
// MODE 1: Obf = bf16(sigmoid(C+bias))     (g)
// MODE 2: Of  = C+bias (fp32)             (s)
// MODE 3: Of  = (C+bias)*G + S (fp32)     (y)
//
// LDS layout per matrix tile: [row 0..255][chunk 0..7] of 16B chunks
// (row stride 128B). Swizzle: LDS chunk (row,c) holds global k-chunk
// c ^ (row&7)  -> every ds_read_b128 frag read is perfectly bank-balanced.
// Staged via global_load_lds (linear LDS dest, pre-swizzled global src).
template <int MODE>
__global__ __launch_bounds__(512, 2) void gemm256(
    const unsigned short* __restrict__ A,
    const unsigned short* __restrict__ Bt,
    const float* __restrict__ bias,
    unsigned short* __restrict__ Obf,
    float* __restrict__ Of,
    const unsigned short* __restrict__ G,
    const float* __restrict__ S) {
  __shared__ __align__(16) unsigned short As[2][BM * BK];  // 32KB x2
  __shared__ __align__(16) unsigned short Bs[2][BN * BK];  // 32KB x2

  const int tid = threadIdx.x;
  const int lane = tid & 63;
  const int wave = tid >> 6;            // 0..7
  const int wm = wave >> 2;             // 0..1  (M half)
  const int wn = wave & 3;              // 0..3  (N quarter)

  // XCD-aware block swizzle: the 4 col-blocks sharing an A row-panel land on
  // the same XCD (xcd = id%8 round-robin). Bijective over 256 blocks.
  const int id = blockIdx.x;
  const int xcd = id & 7;
  const int slot = id >> 3;             // 0..31
  const int rblk = xcd + 8 * (slot >> 2);  // 0..63
  const int cblk = slot & 3;               // 0..3
  const int m0 = rblk * BM, n0 = cblk * BN;

  const unsigned short* gA = A + (size_t)m0 * NDIM;
  const unsigned short* gB = Bt + (size_t)n0 * NDIM;

  f32x4 acc[8][4] = {};

  // ---- staging: one matrix tile (256x64 bf16 = 32KB = 2048 chunks), 4 issues
  auto stage = [&](const unsigned short* gsrc, unsigned short* lds, int kt) {
#pragma unroll
    for (int j = 0; j < 4; ++j) {
      int cid = j * 512 + tid;              // 16B-chunk id in tile
      int row = cid >> 3;                   // 0..255
      int c = (cid & 7) ^ (row & 7);        // pre-swizzled global k-chunk
      const unsigned short* g = gsrc + (size_t)row * NDIM + kt * BK + c * 8;
      unsigned short* l = lds + (j * 512 + (tid & ~63)) * 8;  // wave-uniform base
      __builtin_amdgcn_global_load_lds(
          (__attribute__((address_space(1))) void*)g,
          (__attribute__((address_space(3))) void*)l, 16, 0, 0);
    }
  };

  // ---- fragment readers (swizzled) ----
  // A frags: 4 row-groups (mi0..mi0+3) x 2 k-slices -> dst[mi*2+kk]
  auto ldA = [&](short8* dst, int mi0, const unsigned short* as) {
#pragma unroll
    for (int mi = 0; mi < 4; ++mi)
#pragma unroll
      for (int kk = 0; kk < 2; ++kk) {
        int row = wm * 128 + (mi0 + mi) * 16 + (lane & 15);
        int c = (kk * 4 + (lane >> 4)) ^ (row & 7);
        dst[mi * 2 + kk] = *reinterpret_cast<const short8*>(as + row * BK + c * 8);
      }
  };
  auto ldB = [&](short8* dst, int nj0, const unsigned short* bs) {
#pragma unroll
    for (int nj = 0; nj < 2; ++nj)
#pragma unroll
      for (int kk = 0; kk < 2; ++kk) {
        int row = wn * 64 + (nj0 + nj) * 16 + (lane & 15);
        int c = (kk * 4 + (lane >> 4)) ^ (row & 7);
        dst[nj * 2 + kk] = *reinterpret_cast<const short8*>(bs + row * BK + c * 8);
      }
  };

#define MFMA_Q(A8, B4, MI0, NJ0)                                          \
  do {                                                                    \
    _Pragma("unroll") for (int kk = 0; kk < 2; ++kk)                      \
    _Pragma("unroll") for (int mi = 0; mi < 4; ++mi)                      \
    _Pragma("unroll") for (int nj = 0; nj < 2; ++nj)                      \
      acc[MI0 + mi][NJ0 + nj] = __builtin_amdgcn_mfma_f32_16x16x32_bf16(  \
          A8[mi * 2 + kk], B4[nj * 2 + kk], acc[MI0 + mi][NJ0 + nj], 0, 0, 0); \
  } while (0)

  // ---- prologue: stage tile 0 into buf 0 ----
  stage(gA, &As[0][0], 0);
  stage(gB, &Bs[0][0], 0);
  asm volatile("s_waitcnt vmcnt(0)" ::: "memory");
  __builtin_amdgcn_s_barrier();

  short8 a_[8], b0_[4], b1_[4];

#pragma unroll 2
  for (int t = 0; t < NT; ++t) {
    const int cur = t & 1;
    const int ktn = (t < NT - 1) ? t + 1 : t;   // dummy re-stage on last iter
    const unsigned short* asC = &As[cur][0];
    const unsigned short* bsC = &Bs[cur][0];
    unsigned short* asN = &As[cur ^ 1][0];
    unsigned short* bsN = &Bs[cur ^ 1][0];

    // ---- phase 1: stage A(next), read A[0..3]+B[0..1], MFMA quad (0,0) ----
    stage(gA, asN, ktn);
    ldA(a_, 0, asC);
    ldB(b0_, 0, bsC);
    __builtin_amdgcn_s_barrier();
    __builtin_amdgcn_s_setprio(1);
    MFMA_Q(a_, b0_, 0, 0);
    __builtin_amdgcn_s_setprio(0);
    __builtin_amdgcn_s_barrier();

    // ---- phase 2: stage B(next), read B[2..3], MFMA quad (0,2) ----
    stage(gB, bsN, ktn);
    ldB(b1_, 2, bsC);
    __builtin_amdgcn_s_barrier();
    __builtin_amdgcn_s_setprio(1);
    MFMA_Q(a_, b1_, 0, 2);
    __builtin_amdgcn_s_setprio(0);
    __builtin_amdgcn_s_barrier();

    // ---- phase 3: read A[4..7], MFMA quad (4,0) ----
    ldA(a_, 4, asC);
    __builtin_amdgcn_s_barrier();
    __builtin_amdgcn_s_setprio(1);
    MFMA_Q(a_, b0_, 4, 0);
    __builtin_amdgcn_s_setprio(0);
    __builtin_amdgcn_s_barrier();

    // ---- phase 4: MFMA quad (4,2); wait prefetch; flip ----
    __builtin_amdgcn_s_setprio(1);
    MFMA_Q(a_, b1_, 4, 2);
    __builtin_amdgcn_s_setprio(0);
    asm volatile("s_waitcnt vmcnt(0)" ::: "memory");
    __builtin_amdgcn_s_barrier();
  }

  // ---- epilogue: C/D layout col = lane&15, row = (lane>>4)*4 + r ----
  const int crow0 = m0 + wm * 128;
  const int ccol0 = n0 + wn * 64;
#pragma unroll
  for (int mi = 0; mi < 8; ++mi) {
#pragma unroll
    for (int nj = 0; nj < 4; ++nj) {
      int row = crow0 + mi * 16 + ((lane >> 4) << 2);
      int col = ccol0 + nj * 16 + (lane & 15);
      float bc = bias[col];
#pragma unroll
      for (int r = 0; r < 4; ++r) {
        float v = acc[mi][nj][r] + bc;
        size_t idx = (size_t)(row + r) * NDIM + col;
        if (MODE == 0) {
          Obf[idx] = f2bf(fmaxf(v, 0.f));
        } else if (MODE == 1) {
          Obf[idx] = f2bf(1.f / (1.f + __expf(-v)));
        } else if (MODE == 2) {
          Of[idx] = v;
        } else {
          Of[idx] = v * bf2f(G[idx]) + S[idx];
        }
      }
    }
  }
#undef MFMA_Q
}

// ---------------- in-place LayerNorm over rows of 1024 fp32 ----------------
__global__ __launch_bounds__(256) void layernorm_inplace(
    float* __restrict__ Y, const float* __restrict__ gamma,
    const float* __restrict__ beta) {
  const int tid = threadIdx.x;
  float* y = Y + (size_t)blockIdx.x * NDIM;
  float4 v = reinterpret_cast<const float4*>(y)[tid];
  float s1 = v.x + v.y + v.z + v.w;
  float s2 = v.x * v.x + v.y * v.y + v.z * v.z + v.w * v.w;
#pragma unroll
  for (int o = 32; o > 0; o >>= 1) {
    s1 += __shfl_down(s1, o, 64);
    s2 += __shfl_down(s2, o, 64);
  }
  __shared__ float red[8];
  int wave = tid >> 6, lane = tid & 63;
  if (lane == 0) { red[wave] = s1; red[wave + 4] = s2; }
  __syncthreads();
  float S1 = red[0] + red[1] + red[2] + red[3];
  float S2 = red[4] + red[5] + red[6] + red[7];
  float mu = S1 * (1.f / NDIM);
  float var = S2 * (1.f / NDIM) - mu * mu;
  float inv = rsqrtf(var + 1e-3f);
  float4 gm = reinterpret_cast<const float4*>(gamma)[tid];
  float4 bt = reinterpret_cast<const float4*>(beta)[tid];
  float4 o;
  o.x = (v.x - mu) * inv * gm.x + bt.x;
  o.y = (v.y - mu) * inv * gm.y + bt.y;
  o.z = (v.z - mu) * inv * gm.z + bt.z;
  o.w = (v.w - mu) * inv * gm.w + bt.w;
  reinterpret_cast<float4*>(y)[tid] = o;
}

extern "C" void kernel_launch(void* const* d_in, const int* in_sizes, int n_in,
                              void* d_out, int out_size, void* d_ws, size_t ws_size,
                              hipStream_t stream) {
  const float* inp = (const float*)d_in[0];
  const float* w1 = (const float*)d_in[1];
  const float* b1 = (const float*)d_in[2];
  const float* w2 = (const float*)d_in[3];
  const float* b2 = (const float*)d_in[4];
  const float* wg = (const float*)d_in[5];
  const float* bg = (const float*)d_in[6];
  const float* wsk = (const float*)d_in[7];
  const float* bs = (const float*)d_in[8];
  const float* gamma = (const float*)d_in[9];
  const float* beta = (const float*)d_in[10];

  char* p = (char*)d_ws;
  const size_t act_bf16 = (size_t)M_TOT * NDIM * 2;
  const size_t act_f32 = (size_t)M_TOT * NDIM * 4;
  const size_t w_bf16 = (size_t)NDIM * NDIM * 2;
  unsigned short* Ain = (unsigned short*)p; p += act_bf16;
  unsigned short* H   = (unsigned short*)p; p += act_bf16;
  unsigned short* G   = (unsigned short*)p; p += act_bf16;
  float*          S   = (float*)p;          p += act_f32;
  unsigned short* W1t = (unsigned short*)p; p += w_bf16;
  unsigned short* W2t = (unsigned short*)p; p += w_bf16;
  unsigned short* Wgt = (unsigned short*)p; p += w_bf16;
  unsigned short* Wst = (unsigned short*)p; p += w_bf16;
  float* Y = (float*)d_out;

  cast_in<<<(M_TOT * NDIM / 4 + 255) / 256, 256, 0, stream>>>(inp, Ain, M_TOT * NDIM / 4);
  dim3 tg(32, 32);
  tcast<<<tg, 256, 0, stream>>>(w1, W1t);
  tcast<<<tg, 256, 0, stream>>>(w2, W2t);
  tcast<<<tg, 256, 0, stream>>>(wg, Wgt);
  tcast<<<tg, 256, 0, stream>>>(wsk, Wst);

  const int nblk = (M_TOT / BM) * (NDIM / BN);  // 64*4 = 256
  gemm256<0><<<nblk, 512, 0, stream>>>(Ain, W1t, b1, H, nullptr, nullptr, nullptr);
  gemm256<1><<<nblk, 512, 0, stream>>>(Ain, Wgt, bg, G, nullptr, nullptr, nullptr);
  gemm256<2><<<nblk, 512, 0, stream>>>(Ain, Wst, bs, nullptr, S, nullptr, nullptr);
  gemm256<3><<<nblk, 512, 0, stream>>>(H, W2t, b2, nullptr, Y, G, S);
  layernorm_inplace<<<M_TOT, 256, 0, stream>>>(Y, gamma, beta);
}

// Round 3
// 217.956 us; speedup vs baseline: 1.2383x; 1.1071x over previous
//
#include <hip/hip_runtime.h>
#include <hip/hip_bf16.h>

typedef short short8 __attribute__((ext_vector_type(8)));
typedef float f32x4 __attribute__((ext_vector_type(4)));

#define M_TOT 16384   // B*S = 4*4096
#define NDIM  1024    // D = U = 1024
#define BM 256
#define BN 256
#define BK 64
#define KH 32         // k-half of a K-tile
#define NT (NDIM / BK)   // 16 K-tiles

static __device__ __forceinline__ unsigned short f2bf(float f) {
  unsigned int u = __builtin_bit_cast(unsigned int, f);
  unsigned int r = (u + 0x7fffu + ((u >> 16) & 1u)) >> 16;   // RN-even
  return (unsigned short)r;
}
static __device__ __forceinline__ float bf2f(unsigned short u) {
  return __builtin_bit_cast(float, ((unsigned int)u) << 16);
}

// ---------------- cast inputs fp32 -> bf16, vectorized ----------------
__global__ __launch_bounds__(256) void cast_in(const float* __restrict__ in,
                                               unsigned short* __restrict__ out,
                                               int n4) {
  int i = blockIdx.x * 256 + threadIdx.x;
  if (i >= n4) return;
  float4 v = reinterpret_cast<const float4*>(in)[i];
  ushort4 o;
  o.x = f2bf(v.x); o.y = f2bf(v.y); o.z = f2bf(v.z); o.w = f2bf(v.w);
  reinterpret_cast<ushort4*>(out)[i] = o;
}

// -------- transpose-cast weight fp32 [K=1024][N=1024] -> bf16 [N][K] --------
__global__ __launch_bounds__(256) void tcast(const float* __restrict__ src,
                                             unsigned short* __restrict__ dst) {
  __shared__ unsigned short tile[32][33];
  int bx = blockIdx.x * 32, by = blockIdx.y * 32;
  int x = threadIdx.x & 31, y = threadIdx.x >> 5;  // 32 x 8
#pragma unroll
  for (int i = 0; i < 32; i += 8)
    tile[y + i][x] = f2bf(src[(size_t)(by + y + i) * NDIM + bx + x]);
  __syncthreads();
#pragma unroll
  for (int i = 0; i < 32; i += 8)
    dst[(size_t)(bx + y + i) * NDIM + by + x] = tile[x][y + i];
}

// ============ 256x256 / BK=64, 8-wave, counted-vmcnt phase GEMM ============
// C = A[M][K] * Bt[N][K]^T, K = NDIM.
// MODE 0: Obf = bf16(relu(C+bias))        (h)
// MODE 1: Obf = bf16(sigmoid(C+bias))     (g)
// MODE 2: Of  = C+bias (fp32)             (s)
// MODE 3: Of  = (C+bias)*G + S (fp32)     (y)
//
// LDS: [buf][mat][khalf][row 0..255][32 k-shorts], 16KB per half-tile.
// Swizzle: stored chunk cs holds global k-chunk cs ^ ((row>>1)&3) ->
// ds_read_b128 frag reads are exactly bank-uniform (8 x 4B per bank / wave).
// Staging: 1 half-tile per phase (2 global_load_lds x 512 thr), linear LDS
// dest + pre-swizzled global src.  Waits are COUNTED (vmcnt(4), never 0):
// each half-tile has 4 phases of flight time.
template <int MODE>
__global__ __launch_bounds__(512, 2) void gemm256(
    const unsigned short* __restrict__ A,
    const unsigned short* __restrict__ Bt,
    const float* __restrict__ bias,
    unsigned short* __restrict__ Obf,
    float* __restrict__ Of,
    const unsigned short* __restrict__ G,
    const float* __restrict__ S) {
  __shared__ __align__(16) unsigned short lds[2][2][2][256][KH];  // 128 KB

  const int tid = threadIdx.x;
  const int lane = tid & 63;
  const int wave = tid >> 6;            // 0..7
  const int wm = wave >> 2;             // 0..1  (M half)
  const int wn = wave & 3;              // 0..3  (N quarter)

  // XCD-aware block swizzle: 4 col-blocks sharing an A row-panel -> same XCD.
  const int id = blockIdx.x;
  const int xcd = id & 7;
  const int slot = id >> 3;                // 0..31
  const int rblk = xcd + 8 * (slot >> 2);  // 0..63
  const int cblk = slot & 3;               // 0..3
  const int m0 = rblk * BM, n0 = cblk * BN;

  const unsigned short* gA = A + (size_t)m0 * NDIM;
  const unsigned short* gB = Bt + (size_t)n0 * NDIM;

  f32x4 acc[8][4] = {};

  // stage one half-tile (mat: 0=A,1=B; h: k-half) of K-tile kt into buf
  auto stage = [&](int buf, int mat, int h, const unsigned short* gsrc, int kt) {
#pragma unroll
    for (int j = 0; j < 2; ++j) {
      int cid = j * 512 + tid;             // 16B-chunk id, 0..1023
      int row = cid >> 2;                  // 0..255
      int cs = cid & 3;
      int c = cs ^ ((row >> 1) & 3);       // pre-swizzled global k-chunk
      const unsigned short* g = gsrc + (size_t)row * NDIM + kt * BK + h * KH + c * 8;
      unsigned short* l = &lds[buf][mat][h][0][0] + (size_t)(j * 512 + (tid & ~63)) * 8;
      __builtin_amdgcn_global_load_lds(
          (__attribute__((address_space(1))) void*)g,
          (__attribute__((address_space(3))) void*)l, 16, 0, 0);
    }
  };

  // fragment readers (swizzled)
  auto ldA = [&](short8* dst, int buf, int mih, int kk) {
#pragma unroll
    for (int mi = 0; mi < 4; ++mi) {
      int row = wm * 128 + (mih * 4 + mi) * 16 + (lane & 15);
      int cs = (lane >> 4) ^ ((row >> 1) & 3);
      dst[mi] = *reinterpret_cast<const short8*>(&lds[buf][0][kk][row][cs * 8]);
    }
  };
  auto ldB = [&](short8* dst, int buf, int kk) {
#pragma unroll
    for (int nj = 0; nj < 4; ++nj) {
      int row = wn * 64 + nj * 16 + (lane & 15);
      int cs = (lane >> 4) ^ ((row >> 1) & 3);
      dst[nj] = *reinterpret_cast<const short8*>(&lds[buf][1][kk][row][cs * 8]);
    }
  };

#define MFMA_Q(A4, B4, MI0)                                               \
  do {                                                                    \
    _Pragma("unroll") for (int mi = 0; mi < 4; ++mi)                      \
    _Pragma("unroll") for (int nj = 0; nj < 4; ++nj)                      \
      acc[MI0 + mi][nj] = __builtin_amdgcn_mfma_f32_16x16x32_bf16(        \
          A4[mi], B4[nj], acc[MI0 + mi][nj], 0, 0, 0);                    \
  } while (0)

#define PHASE_TAIL()                                          \
  __builtin_amdgcn_s_barrier();                               \
  asm volatile("s_waitcnt lgkmcnt(0)" ::: "memory");          \
  __builtin_amdgcn_sched_barrier(0)

  // ---- prologue: stage all 4 half-tiles of K-tile 0 into buf 0 ----
  stage(0, 0, 0, gA, 0);
  stage(0, 1, 0, gB, 0);
  stage(0, 0, 1, gA, 0);
  stage(0, 1, 1, gB, 0);
  asm volatile("s_waitcnt vmcnt(4)" ::: "memory");   // A-k0,B-k0 landed
  __builtin_amdgcn_s_barrier();

  short8 a_[4], b0_[4], b1_[4];

#pragma unroll 2
  for (int t = 0; t < NT; ++t) {
    const int cur = t & 1, nxt = cur ^ 1;
    const int ktn = (t < NT - 1) ? t + 1 : t;   // dummy re-stage on last iter

    // ---- phase 1: stage A-k0(next); read A[0..3]k0 + B[*]k0; MFMA (0..3, k0)
    stage(nxt, 0, 0, gA, ktn);
    ldA(a_, cur, 0, 0);
    ldB(b0_, cur, 0);
    PHASE_TAIL();
    __builtin_amdgcn_s_setprio(1);
    MFMA_Q(a_, b0_, 0);
    __builtin_amdgcn_s_setprio(0);
    __builtin_amdgcn_s_barrier();

    // ---- phase 2: stage B-k0(next); read A[4..7]k0; MFMA (4..7, k0)
    stage(nxt, 1, 0, gB, ktn);
    ldA(a_, cur, 1, 0);
    PHASE_TAIL();
    __builtin_amdgcn_s_setprio(1);
    MFMA_Q(a_, b0_, 4);
    __builtin_amdgcn_s_setprio(0);
    asm volatile("s_waitcnt vmcnt(4)" ::: "memory");  // cur's k1 halves landed
    __builtin_amdgcn_s_barrier();

    // ---- phase 3: stage A-k1(next); read A[0..3]k1 + B[*]k1; MFMA (0..3, k1)
    stage(nxt, 0, 1, gA, ktn);
    ldA(a_, cur, 0, 1);
    ldB(b1_, cur, 1);
    PHASE_TAIL();
    __builtin_amdgcn_s_setprio(1);
    MFMA_Q(a_, b1_, 0);
    __builtin_amdgcn_s_setprio(0);
    __builtin_amdgcn_s_barrier();

    // ---- phase 4: stage B-k1(next); read A[4..7]k1; MFMA (4..7, k1)
    stage(nxt, 1, 1, gB, ktn);
    ldA(a_, cur, 1, 1);
    PHASE_TAIL();
    __builtin_amdgcn_s_setprio(1);
    MFMA_Q(a_, b1_, 4);
    __builtin_amdgcn_s_setprio(0);
    asm volatile("s_waitcnt vmcnt(4)" ::: "memory");  // next's k0 halves landed
    __builtin_amdgcn_s_barrier();
  }

  // ---- epilogue: C/D layout col = lane&15, row = (lane>>4)*4 + r ----
  const int crow0 = m0 + wm * 128;
  const int ccol0 = n0 + wn * 64;
#pragma unroll
  for (int mi = 0; mi < 8; ++mi) {
#pragma unroll
    for (int nj = 0; nj < 4; ++nj) {
      int row = crow0 + mi * 16 + ((lane >> 4) << 2);
      int col = ccol0 + nj * 16 + (lane & 15);
      float bc = bias[col];
#pragma unroll
      for (int r = 0; r < 4; ++r) {
        float v = acc[mi][nj][r] + bc;
        size_t idx = (size_t)(row + r) * NDIM + col;
        if (MODE == 0) {
          Obf[idx] = f2bf(fmaxf(v, 0.f));
        } else if (MODE == 1) {
          Obf[idx] = f2bf(1.f / (1.f + __expf(-v)));
        } else if (MODE == 2) {
          Of[idx] = v;
        } else {
          Of[idx] = v * bf2f(G[idx]) + S[idx];
        }
      }
    }
  }
#undef MFMA_Q
#undef PHASE_TAIL
}

// ---------------- in-place LayerNorm over rows of 1024 fp32 ----------------
__global__ __launch_bounds__(256) void layernorm_inplace(
    float* __restrict__ Y, const float* __restrict__ gamma,
    const float* __restrict__ beta) {
  const int tid = threadIdx.x;
  float* y = Y + (size_t)blockIdx.x * NDIM;
  float4 v = reinterpret_cast<const float4*>(y)[tid];
  float s1 = v.x + v.y + v.z + v.w;
  float s2 = v.x * v.x + v.y * v.y + v.z * v.z + v.w * v.w;
#pragma unroll
  for (int o = 32; o > 0; o >>= 1) {
    s1 += __shfl_down(s1, o, 64);
    s2 += __shfl_down(s2, o, 64);
  }
  __shared__ float red[8];
  int wave = tid >> 6, lane = tid & 63;
  if (lane == 0) { red[wave] = s1; red[wave + 4] = s2; }
  __syncthreads();
  float S1 = red[0] + red[1] + red[2] + red[3];
  float S2 = red[4] + red[5] + red[6] + red[7];
  float mu = S1 * (1.f / NDIM);
  float var = S2 * (1.f / NDIM) - mu * mu;
  float inv = rsqrtf(var + 1e-3f);
  float4 gm = reinterpret_cast<const float4*>(gamma)[tid];
  float4 bt = reinterpret_cast<const float4*>(beta)[tid];
  float4 o;
  o.x = (v.x - mu) * inv * gm.x + bt.x;
  o.y = (v.y - mu) * inv * gm.y + bt.y;
  o.z = (v.z - mu) * inv * gm.z + bt.z;
  o.w = (v.w - mu) * inv * gm.w + bt.w;
  reinterpret_cast<float4*>(y)[tid] = o;
}

extern "C" void kernel_launch(void* const* d_in, const int* in_sizes, int n_in,
                              void* d_out, int out_size, void* d_ws, size_t ws_size,
                              hipStream_t stream) {
  const float* inp = (const float*)d_in[0];
  const float* w1 = (const float*)d_in[1];
  const float* b1 = (const float*)d_in[2];
  const float* w2 = (const float*)d_in[3];
  const float* b2 = (const float*)d_in[4];
  const float* wg = (const float*)d_in[5];
  const float* bg = (const float*)d_in[6];
  const float* wsk = (const float*)d_in[7];
  const float* bs = (const float*)d_in[8];
  const float* gamma = (const float*)d_in[9];
  const float* beta = (const float*)d_in[10];

  char* p = (char*)d_ws;
  const size_t act_bf16 = (size_t)M_TOT * NDIM * 2;
  const size_t act_f32 = (size_t)M_TOT * NDIM * 4;
  const size_t w_bf16 = (size_t)NDIM * NDIM * 2;
  unsigned short* Ain = (unsigned short*)p; p += act_bf16;
  unsigned short* H   = (unsigned short*)p; p += act_bf16;
  unsigned short* G   = (unsigned short*)p; p += act_bf16;
  float*          S   = (float*)p;          p += act_f32;
  unsigned short* W1t = (unsigned short*)p; p += w_bf16;
  unsigned short* W2t = (unsigned short*)p; p += w_bf16;
  unsigned short* Wgt = (unsigned short*)p; p += w_bf16;
  unsigned short* Wst = (unsigned short*)p; p += w_bf16;
  float* Y = (float*)d_out;

  cast_in<<<(M_TOT * NDIM / 4 + 255) / 256, 256, 0, stream>>>(inp, Ain, M_TOT * NDIM / 4);
  dim3 tg(32, 32);
  tcast<<<tg, 256, 0, stream>>>(w1, W1t);
  tcast<<<tg, 256, 0, stream>>>(w2, W2t);
  tcast<<<tg, 256, 0, stream>>>(wg, Wgt);
  tcast<<<tg, 256, 0, stream>>>(wsk, Wst);

  const int nblk = (M_TOT / BM) * (NDIM / BN);  // 64*4 = 256
  gemm256<0><<<nblk, 512, 0, stream>>>(Ain, W1t, b1, H, nullptr, nullptr, nullptr);
  gemm256<1><<<nblk, 512, 0, stream>>>(Ain, Wgt, bg, G, nullptr, nullptr, nullptr);
  gemm256<2><<<nblk, 512, 0, stream>>>(Ain, Wst, bs, nullptr, S, nullptr, nullptr);
  gemm256<3><<<nblk, 512, 0, stream>>>(H, W2t, b2, nullptr, Y, G, S);
  layernorm_inplace<<<M_TOT, 256, 0, stream>>>(Y, gamma, beta);
}

// Round 4
// 207.185 us; speedup vs baseline: 1.3027x; 1.0520x over previous
//
#include <hip/hip_runtime.h>
#include <hip/hip_bf16.h>

typedef short short8 __attribute__((ext_vector_type(8)));
typedef float f32x4 __attribute__((ext_vector_type(4)));

#define M_TOT 16384   // B*S = 4*4096
#define NDIM  1024    // D = U = 1024
#define BM 256
#define BN 256
#define BK 64
#define KH 32         // k-half of a K-tile
#define NT (NDIM / BK)   // 16 K-tiles

static __device__ __forceinline__ unsigned short f2bf(float f) {
  unsigned int u = __builtin_bit_cast(unsigned int, f);
  unsigned int r = (u + 0x7fffu + ((u >> 16) & 1u)) >> 16;   // RN-even
  return (unsigned short)r;
}
static __device__ __forceinline__ float bf2f(unsigned short u) {
  return __builtin_bit_cast(float, ((unsigned int)u) << 16);
}

// compile-time-only reorder fence (zero runtime cost)
#define CLB() asm volatile("" ::: "memory")

// ---------------- cast inputs fp32 -> bf16, vectorized ----------------
__global__ __launch_bounds__(256) void cast_in(const float* __restrict__ in,
                                               unsigned short* __restrict__ out,
                                               int n4) {
  int i = blockIdx.x * 256 + threadIdx.x;
  if (i >= n4) return;
  float4 v = reinterpret_cast<const float4*>(in)[i];
  ushort4 o;
  o.x = f2bf(v.x); o.y = f2bf(v.y); o.z = f2bf(v.z); o.w = f2bf(v.w);
  reinterpret_cast<ushort4*>(out)[i] = o;
}

// -------- transpose-cast weight fp32 [K=1024][N=1024] -> bf16 [N][K] --------
__global__ __launch_bounds__(256) void tcast(const float* __restrict__ src,
                                             unsigned short* __restrict__ dst) {
  __shared__ unsigned short tile[32][33];
  int bx = blockIdx.x * 32, by = blockIdx.y * 32;
  int x = threadIdx.x & 31, y = threadIdx.x >> 5;  // 32 x 8
#pragma unroll
  for (int i = 0; i < 32; i += 8)
    tile[y + i][x] = f2bf(src[(size_t)(by + y + i) * NDIM + bx + x]);
  __syncthreads();
#pragma unroll
  for (int i = 0; i < 32; i += 8)
    dst[(size_t)(bx + y + i) * NDIM + by + x] = tile[x][y + i];
}

// ============ 256x256 / BK=64, 8-wave, counted-vmcnt phase GEMM ============
// C = A[M][K] * Bt[N][K]^T, K = NDIM.
// MODE 0: O = bf16(relu(C+bias))          (h)
// MODE 1: O = bf16(sigmoid(C+bias))       (g)
// MODE 2: O = bf16(C+bias)                (s)
// MODE 3: O = bf16((C+bias)*G + S)        (y, pre-LN)
//
// LDS: [buf][mat][khalf][row 0..255][32 k-shorts], 16KB per half-tile.
// Swizzle: stored chunk cs holds global k-chunk cs ^ ((row>>1)&3) ->
// ds_read_b128 frag reads are exactly 2-way bank-uniform (free, m136).
// Staging: 1 half-tile per phase (2 global_load_lds x 512 thr), linear LDS
// dest + pre-swizzled global src.  Waits are COUNTED (vmcnt(4), never 0):
// each half-tile gets ~4 phases of flight.  No sched_barrier / no manual
// lgkmcnt: plain-load dataflow lets the compiler emit fine-grained waits.
template <int MODE>
__global__ __launch_bounds__(512, 2) void gemm256(
    const unsigned short* __restrict__ A,
    const unsigned short* __restrict__ Bt,
    const float* __restrict__ bias,
    unsigned short* __restrict__ O,
    const unsigned short* __restrict__ G,
    const unsigned short* __restrict__ S) {
  __shared__ __align__(16) unsigned short lds[2][2][2][256][KH];  // 128 KB

  const int tid = threadIdx.x;
  const int lane = tid & 63;
  const int wave = tid >> 6;            // 0..7
  const int wm = wave >> 2;             // 0..1  (M half)
  const int wn = wave & 3;              // 0..3  (N quarter)

  // XCD-aware block swizzle: 4 col-blocks sharing an A row-panel -> same XCD.
  const int id = blockIdx.x;
  const int xcd = id & 7;
  const int slot = id >> 3;                // 0..31
  const int rblk = xcd + 8 * (slot >> 2);  // 0..63
  const int cblk = slot & 3;               // 0..3
  const int m0 = rblk * BM, n0 = cblk * BN;

  const unsigned short* gA = A + (size_t)m0 * NDIM;
  const unsigned short* gB = Bt + (size_t)n0 * NDIM;

  f32x4 acc[8][4] = {};

  // stage one half-tile (mat: 0=A,1=B; h: k-half) of K-tile kt into buf
  auto stage = [&](int buf, int mat, int h, const unsigned short* gsrc, int kt) {
#pragma unroll
    for (int j = 0; j < 2; ++j) {
      int cid = j * 512 + tid;             // 16B-chunk id, 0..1023
      int row = cid >> 2;                  // 0..255
      int cs = cid & 3;
      int c = cs ^ ((row >> 1) & 3);       // pre-swizzled global k-chunk
      const unsigned short* g = gsrc + (size_t)row * NDIM + kt * BK + h * KH + c * 8;
      unsigned short* l = &lds[buf][mat][h][0][0] + (size_t)(j * 512 + (tid & ~63)) * 8;
      __builtin_amdgcn_global_load_lds(
          (__attribute__((address_space(1))) void*)g,
          (__attribute__((address_space(3))) void*)l, 16, 0, 0);
    }
  };

  // fragment readers (swizzled)
  auto ldA = [&](short8* dst, int buf, int mih, int kk) {
#pragma unroll
    for (int mi = 0; mi < 4; ++mi) {
      int row = wm * 128 + (mih * 4 + mi) * 16 + (lane & 15);
      int cs = (lane >> 4) ^ ((row >> 1) & 3);
      dst[mi] = *reinterpret_cast<const short8*>(&lds[buf][0][kk][row][cs * 8]);
    }
  };
  auto ldB = [&](short8* dst, int buf, int kk) {
#pragma unroll
    for (int nj = 0; nj < 4; ++nj) {
      int row = wn * 64 + nj * 16 + (lane & 15);
      int cs = (lane >> 4) ^ ((row >> 1) & 3);
      dst[nj] = *reinterpret_cast<const short8*>(&lds[buf][1][kk][row][cs * 8]);
    }
  };

#define MFMA_Q(A4, B4, MI0)                                               \
  do {                                                                    \
    _Pragma("unroll") for (int mi = 0; mi < 4; ++mi)                      \
    _Pragma("unroll") for (int nj = 0; nj < 4; ++nj)                      \
      acc[MI0 + mi][nj] = __builtin_amdgcn_mfma_f32_16x16x32_bf16(        \
          A4[mi], B4[nj], acc[MI0 + mi][nj], 0, 0, 0);                    \
  } while (0)

#define BAR() do { CLB(); __builtin_amdgcn_s_barrier(); CLB(); } while (0)

  // ---- prologue: stage all 4 half-tiles of K-tile 0 into buf 0 ----
  stage(0, 0, 0, gA, 0);
  stage(0, 1, 0, gB, 0);
  stage(0, 0, 1, gA, 0);
  stage(0, 1, 1, gB, 0);
  asm volatile("s_waitcnt vmcnt(4)" ::: "memory");   // A-k0,B-k0 landed
  BAR();

  short8 a_[4], b0_[4], b1_[4];

#pragma unroll 2
  for (int t = 0; t < NT; ++t) {
    const int cur = t & 1, nxt = cur ^ 1;
    const int ktn = (t < NT - 1) ? t + 1 : t;   // dummy re-stage on last iter

    // ---- phase 1: stage A-k0(next); read A[0..3]k0 + B[*]k0; MFMA (0..3, k0)
    stage(nxt, 0, 0, gA, ktn);
    ldA(a_, cur, 0, 0);
    ldB(b0_, cur, 0);
    BAR();
    __builtin_amdgcn_s_setprio(1);
    MFMA_Q(a_, b0_, 0);
    __builtin_amdgcn_s_setprio(0);
    BAR();

    // ---- phase 2: stage B-k0(next); read A[4..7]k0; MFMA (4..7, k0)
    stage(nxt, 1, 0, gB, ktn);
    ldA(a_, cur, 1, 0);
    BAR();
    __builtin_amdgcn_s_setprio(1);
    MFMA_Q(a_, b0_, 4);
    __builtin_amdgcn_s_setprio(0);
    asm volatile("s_waitcnt vmcnt(4)" ::: "memory");  // cur's k1 halves landed
    BAR();

    // ---- phase 3: stage A-k1(next); read A[0..3]k1 + B[*]k1; MFMA (0..3, k1)
    stage(nxt, 0, 1, gA, ktn);
    ldA(a_, cur, 0, 1);
    ldB(b1_, cur, 1);
    BAR();
    __builtin_amdgcn_s_setprio(1);
    MFMA_Q(a_, b1_, 0);
    __builtin_amdgcn_s_setprio(0);
    BAR();

    // ---- phase 4: stage B-k1(next); read A[4..7]k1; MFMA (4..7, k1)
    stage(nxt, 1, 1, gB, ktn);
    ldA(a_, cur, 1, 1);
    BAR();
    __builtin_amdgcn_s_setprio(1);
    MFMA_Q(a_, b1_, 4);
    __builtin_amdgcn_s_setprio(0);
    asm volatile("s_waitcnt vmcnt(4)" ::: "memory");  // next's k0 halves landed
    BAR();
  }

  // ---- epilogue: C/D layout col = lane&15, row = (lane>>4)*4 + r ----
  const int crow0 = m0 + wm * 128;
  const int ccol0 = n0 + wn * 64;
#pragma unroll
  for (int mi = 0; mi < 8; ++mi) {
#pragma unroll
    for (int nj = 0; nj < 4; ++nj) {
      int row = crow0 + mi * 16 + ((lane >> 4) << 2);
      int col = ccol0 + nj * 16 + (lane & 15);
      float bc = bias[col];
#pragma unroll
      for (int r = 0; r < 4; ++r) {
        float v = acc[mi][nj][r] + bc;
        size_t idx = (size_t)(row + r) * NDIM + col;
        if (MODE == 0) {
          O[idx] = f2bf(fmaxf(v, 0.f));
        } else if (MODE == 1) {
          O[idx] = f2bf(1.f / (1.f + __expf(-v)));
        } else if (MODE == 2) {
          O[idx] = f2bf(v);
        } else {
          O[idx] = f2bf(v * bf2f(G[idx]) + bf2f(S[idx]));
        }
      }
    }
  }
#undef MFMA_Q
#undef BAR
}

// -------- LayerNorm: bf16 rows in, fp32 out --------
__global__ __launch_bounds__(256) void layernorm_bf(
    const unsigned short* __restrict__ Ybf, float* __restrict__ Out,
    const float* __restrict__ gamma, const float* __restrict__ beta) {
  const int tid = threadIdx.x;
  const unsigned short* y = Ybf + (size_t)blockIdx.x * NDIM;
  ushort4 u = reinterpret_cast<const ushort4*>(y)[tid];
  float v0 = bf2f(u.x), v1 = bf2f(u.y), v2 = bf2f(u.z), v3 = bf2f(u.w);
  float s1 = v0 + v1 + v2 + v3;
  float s2 = v0 * v0 + v1 * v1 + v2 * v2 + v3 * v3;
#pragma unroll
  for (int o = 32; o > 0; o >>= 1) {
    s1 += __shfl_down(s1, o, 64);
    s2 += __shfl_down(s2, o, 64);
  }
  __shared__ float red[8];
  int wave = tid >> 6, lane = tid & 63;
  if (lane == 0) { red[wave] = s1; red[wave + 4] = s2; }
  __syncthreads();
  float S1 = red[0] + red[1] + red[2] + red[3];
  float S2 = red[4] + red[5] + red[6] + red[7];
  float mu = S1 * (1.f / NDIM);
  float var = S2 * (1.f / NDIM) - mu * mu;
  float inv = rsqrtf(var + 1e-3f);
  float4 gm = reinterpret_cast<const float4*>(gamma)[tid];
  float4 bt = reinterpret_cast<const float4*>(beta)[tid];
  float4 o;
  o.x = (v0 - mu) * inv * gm.x + bt.x;
  o.y = (v1 - mu) * inv * gm.y + bt.y;
  o.z = (v2 - mu) * inv * gm.z + bt.z;
  o.w = (v3 - mu) * inv * gm.w + bt.w;
  reinterpret_cast<float4*>(Out + (size_t)blockIdx.x * NDIM)[tid] = o;
}

extern "C" void kernel_launch(void* const* d_in, const int* in_sizes, int n_in,
                              void* d_out, int out_size, void* d_ws, size_t ws_size,
                              hipStream_t stream) {
  const float* inp = (const float*)d_in[0];
  const float* w1 = (const float*)d_in[1];
  const float* b1 = (const float*)d_in[2];
  const float* w2 = (const float*)d_in[3];
  const float* b2 = (const float*)d_in[4];
  const float* wg = (const float*)d_in[5];
  const float* bg = (const float*)d_in[6];
  const float* wsk = (const float*)d_in[7];
  const float* bs = (const float*)d_in[8];
  const float* gamma = (const float*)d_in[9];
  const float* beta = (const float*)d_in[10];

  char* p = (char*)d_ws;
  const size_t act_bf16 = (size_t)M_TOT * NDIM * 2;
  const size_t w_bf16 = (size_t)NDIM * NDIM * 2;
  unsigned short* Ain = (unsigned short*)p; p += act_bf16;
  unsigned short* H   = (unsigned short*)p; p += act_bf16;
  unsigned short* G   = (unsigned short*)p; p += act_bf16;
  unsigned short* S   = (unsigned short*)p; p += act_bf16;
  unsigned short* Ybf = (unsigned short*)p; p += act_bf16;
  unsigned short* W1t = (unsigned short*)p; p += w_bf16;
  unsigned short* W2t = (unsigned short*)p; p += w_bf16;
  unsigned short* Wgt = (unsigned short*)p; p += w_bf16;
  unsigned short* Wst = (unsigned short*)p; p += w_bf16;

  cast_in<<<(M_TOT * NDIM / 4 + 255) / 256, 256, 0, stream>>>(inp, Ain, M_TOT * NDIM / 4);
  dim3 tg(32, 32);
  tcast<<<tg, 256, 0, stream>>>(w1, W1t);
  tcast<<<tg, 256, 0, stream>>>(w2, W2t);
  tcast<<<tg, 256, 0, stream>>>(wg, Wgt);
  tcast<<<tg, 256, 0, stream>>>(wsk, Wst);

  const int nblk = (M_TOT / BM) * (NDIM / BN);  // 64*4 = 256
  gemm256<0><<<nblk, 512, 0, stream>>>(Ain, W1t, b1, H, nullptr, nullptr);
  gemm256<1><<<nblk, 512, 0, stream>>>(Ain, Wgt, bg, G, nullptr, nullptr);
  gemm256<2><<<nblk, 512, 0, stream>>>(Ain, Wst, bs, S, nullptr, nullptr);
  gemm256<3><<<nblk, 512, 0, stream>>>(H, W2t, b2, Ybf, G, S);
  layernorm_bf<<<M_TOT, 256, 0, stream>>>(Ybf, (float*)d_out, gamma, beta);
}

// Round 5
// 201.603 us; speedup vs baseline: 1.3387x; 1.0277x over previous
//
#include <hip/hip_runtime.h>
#include <hip/hip_bf16.h>

typedef short short8 __attribute__((ext_vector_type(8)));
typedef float f32x4 __attribute__((ext_vector_type(4)));

#define M_TOT 16384   // B*S = 4*4096
#define NDIM  1024    // D = U = 1024
#define BM 256
#define BN 256
#define BK 32
#define NT (NDIM / BK)   // 32 K-tiles

static __device__ __forceinline__ unsigned short f2bf(float f) {
  unsigned int u = __builtin_bit_cast(unsigned int, f);
  unsigned int r = (u + 0x7fffu + ((u >> 16) & 1u)) >> 16;   // RN-even
  return (unsigned short)r;
}
static __device__ __forceinline__ float bf2f(unsigned short u) {
  return __builtin_bit_cast(float, ((unsigned int)u) << 16);
}

// compile-time-only reorder fence (zero runtime cost)
#define CLB() asm volatile("" ::: "memory")

// ---------------- cast inputs fp32 -> bf16, vectorized ----------------
__global__ __launch_bounds__(256) void cast_in(const float* __restrict__ in,
                                               unsigned short* __restrict__ out,
                                               int n4) {
  int i = blockIdx.x * 256 + threadIdx.x;
  if (i >= n4) return;
  float4 v = reinterpret_cast<const float4*>(in)[i];
  ushort4 o;
  o.x = f2bf(v.x); o.y = f2bf(v.y); o.z = f2bf(v.z); o.w = f2bf(v.w);
  reinterpret_cast<ushort4*>(out)[i] = o;
}

// -------- transpose-cast weight fp32 [K=1024][N=1024] -> bf16 [N][K] --------
__global__ __launch_bounds__(256) void tcast(const float* __restrict__ src,
                                             unsigned short* __restrict__ dst) {
  __shared__ unsigned short tile[32][33];
  int bx = blockIdx.x * 32, by = blockIdx.y * 32;
  int x = threadIdx.x & 31, y = threadIdx.x >> 5;  // 32 x 8
#pragma unroll
  for (int i = 0; i < 32; i += 8)
    tile[y + i][x] = f2bf(src[(size_t)(by + y + i) * NDIM + bx + x]);
  __syncthreads();
#pragma unroll
  for (int i = 0; i < 32; i += 8)
    dst[(size_t)(bx + y + i) * NDIM + by + x] = tile[x][y + i];
}

// ========== 256x256 / BK=32, 8-wave, 4-slot LDS ring bf16 MFMA GEMM ==========
// C = A[M][K] * Bt[N][K]^T, K = NDIM.
// MODE 0: O = bf16(relu(C+bias))          (h)
// MODE 1: O = bf16(sigmoid(C+bias))       (g)
// MODE 2: O = bf16(C+bias)                (s)
// MODE 3: O = bf16((C+bias)*G + S)        (y, pre-LN)
//
// LDS: 4-slot ring, lds[slot][mat][row 0..255][32 k-shorts] = 128 KB.
// Staging runs 3 K-tiles ahead (12 loads/thread in flight); ONE counted
// vmcnt(8) + ONE raw s_barrier per tile — loads are never drained to 0 in
// the steady state, and there is no mid-tile barrier: the compiler
// interleaves the 12 ds_read_b128 with the 32 MFMAs per wave (fine-grained
// lgkmcnt), and waves desync within a tile so LDS and MFMA pipes overlap.
// Swizzle: stored chunk cs holds global k-chunk cs ^ ((row>>1)&3) ->
// frag reads are 2-way bank-uniform (free, m136).
// Ring safety: slot of tile u is re-staged during tile u-3, one full tile
// after its last read was drained at the (u-4) end-barrier.
template <int MODE>
__global__ __launch_bounds__(512, 2) void gemm256(
    const unsigned short* __restrict__ A,
    const unsigned short* __restrict__ Bt,
    const float* __restrict__ bias,
    unsigned short* __restrict__ O,
    const unsigned short* __restrict__ G,
    const unsigned short* __restrict__ S) {
  __shared__ __align__(16) unsigned short lds[4][2][256][BK];  // 128 KB

  const int tid = threadIdx.x;
  const int lane = tid & 63;
  const int wave = tid >> 6;            // 0..7
  const int wm = wave >> 2;             // 0..1  (M half)
  const int wn = wave & 3;              // 0..3  (N quarter)

  // XCD-aware block swizzle: 4 col-blocks sharing an A row-panel -> same XCD.
  const int id = blockIdx.x;
  const int xcd = id & 7;
  const int slot0 = id >> 3;               // 0..31
  const int rblk = xcd + 8 * (slot0 >> 2); // 0..63
  const int cblk = slot0 & 3;              // 0..3
  const int m0 = rblk * BM, n0 = cblk * BN;

  const unsigned short* gA = A + (size_t)m0 * NDIM;
  const unsigned short* gB = Bt + (size_t)n0 * NDIM;

  f32x4 acc[8][4] = {};

  // stage K-tile kt (A 16KB + B 16KB = 2048 chunks) into ring slot: 4 loads/thr
  auto stage = [&](int slot, int kt) {
#pragma unroll
    for (int q = 0; q < 4; ++q) {
      int cid = q * 512 + tid;             // 16B-chunk id, 0..2047
      int mat = q >> 1;                    // q=0,1 -> A ; q=2,3 -> B
      int local = cid & 1023;
      int row = local >> 2;                // 0..255
      int c = (local & 3) ^ ((row >> 1) & 3);  // pre-swizzled global k-chunk
      const unsigned short* g =
          (mat ? gB : gA) + (size_t)row * NDIM + kt * BK + c * 8;
      unsigned short* l = &lds[slot][mat][0][0] +
                          (size_t)((q * 512 + (tid & ~63)) & 1023) * 8;  // wave-uniform
      __builtin_amdgcn_global_load_lds(
          (__attribute__((address_space(1))) void*)g,
          (__attribute__((address_space(3))) void*)l, 16, 0, 0);
    }
  };

  // read fragments of a slot and do its 32 MFMAs
  auto compute = [&](int slot) {
    short8 af[8], bf[4];
#pragma unroll
    for (int nj = 0; nj < 4; ++nj) {
      int row = wn * 64 + nj * 16 + (lane & 15);
      int cs = (lane >> 4) ^ ((row >> 1) & 3);
      bf[nj] = *reinterpret_cast<const short8*>(&lds[slot][1][row][cs * 8]);
    }
#pragma unroll
    for (int mi = 0; mi < 8; ++mi) {
      int row = wm * 128 + mi * 16 + (lane & 15);
      int cs = (lane >> 4) ^ ((row >> 1) & 3);
      af[mi] = *reinterpret_cast<const short8*>(&lds[slot][0][row][cs * 8]);
    }
    __builtin_amdgcn_s_setprio(1);
#pragma unroll
    for (int mi = 0; mi < 8; ++mi)
#pragma unroll
      for (int nj = 0; nj < 4; ++nj)
        acc[mi][nj] = __builtin_amdgcn_mfma_f32_16x16x32_bf16(
            af[mi], bf[nj], acc[mi][nj], 0, 0, 0);
    __builtin_amdgcn_s_setprio(0);
  };

#define VMW(N) asm volatile("s_waitcnt vmcnt(" #N ")" ::: "memory")
#define BAR() do { CLB(); __builtin_amdgcn_s_barrier(); CLB(); } while (0)

  // ---- prologue: stage tiles 0,1,2 (12 loads); tile 0 landed at vmcnt(8) ----
  stage(0, 0);
  stage(1, 1);
  stage(2, 2);
  VMW(8);
  BAR();

  // ---- steady state: one barrier + one counted vmcnt per tile ----
#pragma unroll 4
  for (int t = 0; t < NT - 4; ++t) {       // t = 0..27, stages tiles 3..30
    stage((t + 3) & 3, t + 3);
    compute(t & 3);
    VMW(8);                                // tile t+1 landed (t+2,t+3 in flight)
    BAR();
  }
  // ---- tail peel: t = 28..31 ----
  stage(3, 31);                            // t=28 stages last tile
  compute(0);
  VMW(8);                                  // tile 29 landed
  BAR();
  compute(1);                              // t=29
  VMW(4);                                  // tile 30 landed
  BAR();
  compute(2);                              // t=30
  VMW(0);                                  // tile 31 landed
  BAR();
  compute(3);                              // t=31

  // ---- epilogue: C/D layout col = lane&15, row = (lane>>4)*4 + r ----
  const int crow0 = m0 + wm * 128;
  const int ccol0 = n0 + wn * 64;
#pragma unroll
  for (int mi = 0; mi < 8; ++mi) {
#pragma unroll
    for (int nj = 0; nj < 4; ++nj) {
      int row = crow0 + mi * 16 + ((lane >> 4) << 2);
      int col = ccol0 + nj * 16 + (lane & 15);
      float bc = bias[col];
#pragma unroll
      for (int r = 0; r < 4; ++r) {
        float v = acc[mi][nj][r] + bc;
        size_t idx = (size_t)(row + r) * NDIM + col;
        if (MODE == 0) {
          O[idx] = f2bf(fmaxf(v, 0.f));
        } else if (MODE == 1) {
          O[idx] = f2bf(1.f / (1.f + __expf(-v)));
        } else if (MODE == 2) {
          O[idx] = f2bf(v);
        } else {
          O[idx] = f2bf(v * bf2f(G[idx]) + bf2f(S[idx]));
        }
      }
    }
  }
#undef VMW
#undef BAR
}

// -------- LayerNorm: bf16 rows in, fp32 out --------
__global__ __launch_bounds__(256) void layernorm_bf(
    const unsigned short* __restrict__ Ybf, float* __restrict__ Out,
    const float* __restrict__ gamma, const float* __restrict__ beta) {
  const int tid = threadIdx.x;
  const unsigned short* y = Ybf + (size_t)blockIdx.x * NDIM;
  ushort4 u = reinterpret_cast<const ushort4*>(y)[tid];
  float v0 = bf2f(u.x), v1 = bf2f(u.y), v2 = bf2f(u.z), v3 = bf2f(u.w);
  float s1 = v0 + v1 + v2 + v3;
  float s2 = v0 * v0 + v1 * v1 + v2 * v2 + v3 * v3;
#pragma unroll
  for (int o = 32; o > 0; o >>= 1) {
    s1 += __shfl_down(s1, o, 64);
    s2 += __shfl_down(s2, o, 64);
  }
  __shared__ float red[8];
  int wave = tid >> 6, lane = tid & 63;
  if (lane == 0) { red[wave] = s1; red[wave + 4] = s2; }
  __syncthreads();
  float S1 = red[0] + red[1] + red[2] + red[3];
  float S2 = red[4] + red[5] + red[6] + red[7];
  float mu = S1 * (1.f / NDIM);
  float var = S2 * (1.f / NDIM) - mu * mu;
  float inv = rsqrtf(var + 1e-3f);
  float4 gm = reinterpret_cast<const float4*>(gamma)[tid];
  float4 bt = reinterpret_cast<const float4*>(beta)[tid];
  float4 o;
  o.x = (v0 - mu) * inv * gm.x + bt.x;
  o.y = (v1 - mu) * inv * gm.y + bt.y;
  o.z = (v2 - mu) * inv * gm.z + bt.z;
  o.w = (v3 - mu) * inv * gm.w + bt.w;
  reinterpret_cast<float4*>(Out + (size_t)blockIdx.x * NDIM)[tid] = o;
}

extern "C" void kernel_launch(void* const* d_in, const int* in_sizes, int n_in,
                              void* d_out, int out_size, void* d_ws, size_t ws_size,
                              hipStream_t stream) {
  const float* inp = (const float*)d_in[0];
  const float* w1 = (const float*)d_in[1];
  const float* b1 = (const float*)d_in[2];
  const float* w2 = (const float*)d_in[3];
  const float* b2 = (const float*)d_in[4];
  const float* wg = (const float*)d_in[5];
  const float* bg = (const float*)d_in[6];
  const float* wsk = (const float*)d_in[7];
  const float* bs = (const float*)d_in[8];
  const float* gamma = (const float*)d_in[9];
  const float* beta = (const float*)d_in[10];

  char* p = (char*)d_ws;
  const size_t act_bf16 = (size_t)M_TOT * NDIM * 2;
  const size_t w_bf16 = (size_t)NDIM * NDIM * 2;
  unsigned short* Ain = (unsigned short*)p; p += act_bf16;
  unsigned short* H   = (unsigned short*)p; p += act_bf16;
  unsigned short* G   = (unsigned short*)p; p += act_bf16;
  unsigned short* S   = (unsigned short*)p; p += act_bf16;
  unsigned short* Ybf = (unsigned short*)p; p += act_bf16;
  unsigned short* W1t = (unsigned short*)p; p += w_bf16;
  unsigned short* W2t = (unsigned short*)p; p += w_bf16;
  unsigned short* Wgt = (unsigned short*)p; p += w_bf16;
  unsigned short* Wst = (unsigned short*)p; p += w_bf16;

  cast_in<<<(M_TOT * NDIM / 4 + 255) / 256, 256, 0, stream>>>(inp, Ain, M_TOT * NDIM / 4);
  dim3 tg(32, 32);
  tcast<<<tg, 256, 0, stream>>>(w1, W1t);
  tcast<<<tg, 256, 0, stream>>>(w2, W2t);
  tcast<<<tg, 256, 0, stream>>>(wg, Wgt);
  tcast<<<tg, 256, 0, stream>>>(wsk, Wst);

  const int nblk = (M_TOT / BM) * (NDIM / BN);  // 64*4 = 256
  gemm256<0><<<nblk, 512, 0, stream>>>(Ain, W1t, b1, H, nullptr, nullptr);
  gemm256<1><<<nblk, 512, 0, stream>>>(Ain, Wgt, bg, G, nullptr, nullptr);
  gemm256<2><<<nblk, 512, 0, stream>>>(Ain, Wst, bs, S, nullptr, nullptr);
  gemm256<3><<<nblk, 512, 0, stream>>>(H, W2t, b2, Ybf, G, S);
  layernorm_bf<<<M_TOT, 256, 0, stream>>>(Ybf, (float*)d_out, gamma, beta);
}

// Round 6
// 195.219 us; speedup vs baseline: 1.3825x; 1.0327x over previous
//
#include <hip/hip_runtime.h>
#include <hip/hip_bf16.h>

typedef short short8 __attribute__((ext_vector_type(8)));
typedef float f32x4 __attribute__((ext_vector_type(4)));

#define M_TOT 16384   // B*S = 4*4096
#define NDIM  1024    // D = U = 1024
#define BK 32
#define NT (NDIM / BK)   // 32 K-tiles

static __device__ __forceinline__ unsigned short f2bf(float f) {
  unsigned int u = __builtin_bit_cast(unsigned int, f);
  unsigned int r = (u + 0x7fffu + ((u >> 16) & 1u)) >> 16;   // RN-even
  return (unsigned short)r;
}
static __device__ __forceinline__ float bf2f(unsigned short u) {
  return __builtin_bit_cast(float, ((unsigned int)u) << 16);
}

// compile-time-only reorder fence (zero runtime cost)
#define CLB() asm volatile("" ::: "memory")
#define VMW(N) asm volatile("s_waitcnt vmcnt(" #N ")" ::: "memory")
#define BAR() do { CLB(); __builtin_amdgcn_s_barrier(); CLB(); } while (0)

// ---------------- cast inputs fp32 -> bf16, vectorized ----------------
__global__ __launch_bounds__(256) void cast_in(const float* __restrict__ in,
                                               unsigned short* __restrict__ out,
                                               int n4) {
  int i = blockIdx.x * 256 + threadIdx.x;
  if (i >= n4) return;
  float4 v = reinterpret_cast<const float4*>(in)[i];
  ushort4 o;
  o.x = f2bf(v.x); o.y = f2bf(v.y); o.z = f2bf(v.z); o.w = f2bf(v.w);
  reinterpret_cast<ushort4*>(out)[i] = o;
}

// -------- transpose-cast weight fp32 [K=1024][N=1024] -> bf16 [N][K] --------
__global__ __launch_bounds__(256) void tcast(const float* __restrict__ src,
                                             unsigned short* __restrict__ dst) {
  __shared__ unsigned short tile[32][33];
  int bx = blockIdx.x * 32, by = blockIdx.y * 32;
  int x = threadIdx.x & 31, y = threadIdx.x >> 5;  // 32 x 8
#pragma unroll
  for (int i = 0; i < 32; i += 8)
    tile[y + i][x] = f2bf(src[(size_t)(by + y + i) * NDIM + bx + x]);
  __syncthreads();
#pragma unroll
  for (int i = 0; i < 32; i += 8)
    dst[(size_t)(bx + y + i) * NDIM + by + x] = tile[x][y + i];
}

// ========== tri-GEMM: stage A once, multiply against 3 weights ==========
// H = bf16(relu(x@W1+b1)); G = bf16(sigmoid(x@Wg+bg)); S = bf16(x@Ws+bs)
// 128x128 tile per block per weight, 256 thr (4 waves, 2x2), BK=32.
// LDS: lds[buf][mat][128][32], mat 0=A, 1..3=W1,Wg,Ws; 64 KB total ->
// 2 blocks/CU, independently barriered (cross-block MFMA/stage overlap).
// Swizzle: stored chunk cs holds global k-chunk cs^((row>>1)&3) (0-conflict,
// measured r4/r5).  Counted vmcnt: next tile staged before VMW(8) so the
// current tile's 8 loads are the only ones waited on; never drains to 0
// except the final tile.
__global__ __launch_bounds__(256, 2) void trigemm(
    const unsigned short* __restrict__ A,
    const unsigned short* __restrict__ W1t,
    const unsigned short* __restrict__ Wgt,
    const unsigned short* __restrict__ Wst,
    const float* __restrict__ b1,
    const float* __restrict__ bg,
    const float* __restrict__ bs,
    unsigned short* __restrict__ H,
    unsigned short* __restrict__ G,
    unsigned short* __restrict__ S) {
  __shared__ __align__(16) unsigned short lds[2][4][128][BK];  // 64 KB

  const int tid = threadIdx.x;
  const int lane = tid & 63;
  const int wave = tid >> 6;            // 0..3
  const int wm = wave >> 1;             // 0..1
  const int wn = wave & 1;              // 0..1

  // XCD swizzle: 8 col-blocks sharing an A row-panel -> same XCD. Bijective
  // over 1024 blocks (id <-> xcd, slot>>3, cblk).
  const int id = blockIdx.x;
  const int xcd = id & 7;
  const int slot = id >> 3;                // 0..127
  const int rblk = xcd + 8 * (slot >> 3);  // 0..127
  const int cblk = slot & 7;               // 0..7
  const int m0 = rblk * 128, n0 = cblk * 128;

  const unsigned short* gA = A + (size_t)m0 * NDIM;
  const unsigned short* gW[3] = {W1t + (size_t)n0 * NDIM, Wgt + (size_t)n0 * NDIM,
                                 Wst + (size_t)n0 * NDIM};

  f32x4 acc[3][4][4] = {};

  // stage K-tile kt (A 8KB + 3xB 8KB = 2048 chunks) into buf: 8 loads/thread
  auto stage = [&](int buf, int kt) {
#pragma unroll
    for (int q = 0; q < 8; ++q) {
      const int mat = q >> 1;              // compile-time: 0=A,1..3=W
      int local = (q & 1) * 256 + tid;     // chunk within mat, 0..511
      int row = local >> 2;                // 0..127
      int c = (local & 3) ^ ((row >> 1) & 3);  // pre-swizzled global k-chunk
      const unsigned short* g =
          (mat == 0 ? gA : gW[mat - 1]) + (size_t)row * NDIM + kt * BK + c * 8;
      unsigned short* l = &lds[buf][0][0][0] +
                          (size_t)(q * 256 + (tid & ~63)) * 8;  // wave-uniform base
      __builtin_amdgcn_global_load_lds(
          (__attribute__((address_space(1))) void*)g,
          (__attribute__((address_space(3))) void*)l, 16, 0, 0);
    }
  };

  auto compute = [&](int buf) {
    short8 af[4];
#pragma unroll
    for (int mi = 0; mi < 4; ++mi) {
      int row = wm * 64 + mi * 16 + (lane & 15);
      int cs = (lane >> 4) ^ ((row >> 1) & 3);
      af[mi] = *reinterpret_cast<const short8*>(&lds[buf][0][row][cs * 8]);
    }
#pragma unroll
    for (int w = 0; w < 3; ++w) {
      short8 bf[4];
#pragma unroll
      for (int nj = 0; nj < 4; ++nj) {
        int row = wn * 64 + nj * 16 + (lane & 15);
        int cs = (lane >> 4) ^ ((row >> 1) & 3);
        bf[nj] = *reinterpret_cast<const short8*>(&lds[buf][1 + w][row][cs * 8]);
      }
      __builtin_amdgcn_s_setprio(1);
#pragma unroll
      for (int mi = 0; mi < 4; ++mi)
#pragma unroll
        for (int nj = 0; nj < 4; ++nj)
          acc[w][mi][nj] = __builtin_amdgcn_mfma_f32_16x16x32_bf16(
              af[mi], bf[nj], acc[w][mi][nj], 0, 0, 0);
      __builtin_amdgcn_s_setprio(0);
    }
  };

  stage(0, 0);
  for (int t = 0; t < NT; ++t) {
    const int cur = t & 1;
    if (t + 1 < NT) {
      stage(cur ^ 1, t + 1);   // writes buf last read at iter t-1 (guarded by
      VMW(8);                  // that iter's end-barrier); tile t landed here
    } else {
      VMW(0);
    }
    BAR();
    compute(cur);
    BAR();
  }

  // epilogue: C/D layout col = lane&15, row = (lane>>4)*4 + r
  const int crow0 = m0 + wm * 64;
  const int ccol0 = n0 + wn * 64;
#pragma unroll
  for (int w = 0; w < 3; ++w) {
    const float* bptr = (w == 0) ? b1 : (w == 1) ? bg : bs;
    unsigned short* optr = (w == 0) ? H : (w == 1) ? G : S;
#pragma unroll
    for (int mi = 0; mi < 4; ++mi) {
#pragma unroll
      for (int nj = 0; nj < 4; ++nj) {
        int row = crow0 + mi * 16 + ((lane >> 4) << 2);
        int col = ccol0 + nj * 16 + (lane & 15);
        float bc = bptr[col];
#pragma unroll
        for (int r = 0; r < 4; ++r) {
          float v = acc[w][mi][nj][r] + bc;
          if (w == 0) v = fmaxf(v, 0.f);
          else if (w == 1) v = 1.f / (1.f + __expf(-v));
          optr[(size_t)(row + r) * NDIM + col] = f2bf(v);
        }
      }
    }
  }
}

// ========== 256x256 / BK=32, 8-wave, 4-slot LDS ring: y-GEMM ==========
// O = bf16((H@W2t^T + b2) * G + S)
__global__ __launch_bounds__(512, 2) void gemm_y(
    const unsigned short* __restrict__ A,
    const unsigned short* __restrict__ Bt,
    const float* __restrict__ bias,
    unsigned short* __restrict__ O,
    const unsigned short* __restrict__ G,
    const unsigned short* __restrict__ S) {
  __shared__ __align__(16) unsigned short lds[4][2][256][BK];  // 128 KB

  const int tid = threadIdx.x;
  const int lane = tid & 63;
  const int wave = tid >> 6;            // 0..7
  const int wm = wave >> 2;             // 0..1
  const int wn = wave & 3;              // 0..3

  const int id = blockIdx.x;
  const int xcd = id & 7;
  const int slot0 = id >> 3;               // 0..31
  const int rblk = xcd + 8 * (slot0 >> 2); // 0..63
  const int cblk = slot0 & 3;              // 0..3
  const int m0 = rblk * 256, n0 = cblk * 256;

  const unsigned short* gA = A + (size_t)m0 * NDIM;
  const unsigned short* gB = Bt + (size_t)n0 * NDIM;

  f32x4 acc[8][4] = {};

  auto stage = [&](int slot, int kt) {
#pragma unroll
    for (int q = 0; q < 4; ++q) {
      int cid = q * 512 + tid;
      int mat = q >> 1;
      int local = cid & 1023;
      int row = local >> 2;
      int c = (local & 3) ^ ((row >> 1) & 3);
      const unsigned short* g =
          (mat ? gB : gA) + (size_t)row * NDIM + kt * BK + c * 8;
      unsigned short* l = &lds[slot][mat][0][0] +
                          (size_t)((q * 512 + (tid & ~63)) & 1023) * 8;
      __builtin_amdgcn_global_load_lds(
          (__attribute__((address_space(1))) void*)g,
          (__attribute__((address_space(3))) void*)l, 16, 0, 0);
    }
  };

  auto compute = [&](int slot) {
    short8 af[8], bf[4];
#pragma unroll
    for (int nj = 0; nj < 4; ++nj) {
      int row = wn * 64 + nj * 16 + (lane & 15);
      int cs = (lane >> 4) ^ ((row >> 1) & 3);
      bf[nj] = *reinterpret_cast<const short8*>(&lds[slot][1][row][cs * 8]);
    }
#pragma unroll
    for (int mi = 0; mi < 8; ++mi) {
      int row = wm * 128 + mi * 16 + (lane & 15);
      int cs = (lane >> 4) ^ ((row >> 1) & 3);
      af[mi] = *reinterpret_cast<const short8*>(&lds[slot][0][row][cs * 8]);
    }
    __builtin_amdgcn_s_setprio(1);
#pragma unroll
    for (int mi = 0; mi < 8; ++mi)
#pragma unroll
      for (int nj = 0; nj < 4; ++nj)
        acc[mi][nj] = __builtin_amdgcn_mfma_f32_16x16x32_bf16(
            af[mi], bf[nj], acc[mi][nj], 0, 0, 0);
    __builtin_amdgcn_s_setprio(0);
  };

  stage(0, 0);
  stage(1, 1);
  stage(2, 2);
  VMW(8);
  BAR();

#pragma unroll 4
  for (int t = 0; t < NT - 4; ++t) {
    stage((t + 3) & 3, t + 3);
    compute(t & 3);
    VMW(8);
    BAR();
  }
  stage(3, 31);
  compute(0);
  VMW(8);
  BAR();
  compute(1);
  VMW(4);
  BAR();
  compute(2);
  VMW(0);
  BAR();
  compute(3);

  const int crow0 = m0 + wm * 128;
  const int ccol0 = n0 + wn * 64;
#pragma unroll
  for (int mi = 0; mi < 8; ++mi) {
#pragma unroll
    for (int nj = 0; nj < 4; ++nj) {
      int row = crow0 + mi * 16 + ((lane >> 4) << 2);
      int col = ccol0 + nj * 16 + (lane & 15);
      float bc = bias[col];
#pragma unroll
      for (int r = 0; r < 4; ++r) {
        float v = acc[mi][nj][r] + bc;
        size_t idx = (size_t)(row + r) * NDIM + col;
        O[idx] = f2bf(v * bf2f(G[idx]) + bf2f(S[idx]));
      }
    }
  }
}

// -------- LayerNorm: bf16 rows in, fp32 out --------
__global__ __launch_bounds__(256) void layernorm_bf(
    const unsigned short* __restrict__ Ybf, float* __restrict__ Out,
    const float* __restrict__ gamma, const float* __restrict__ beta) {
  const int tid = threadIdx.x;
  const unsigned short* y = Ybf + (size_t)blockIdx.x * NDIM;
  ushort4 u = reinterpret_cast<const ushort4*>(y)[tid];
  float v0 = bf2f(u.x), v1 = bf2f(u.y), v2 = bf2f(u.z), v3 = bf2f(u.w);
  float s1 = v0 + v1 + v2 + v3;
  float s2 = v0 * v0 + v1 * v1 + v2 * v2 + v3 * v3;
#pragma unroll
  for (int o = 32; o > 0; o >>= 1) {
    s1 += __shfl_down(s1, o, 64);
    s2 += __shfl_down(s2, o, 64);
  }
  __shared__ float red[8];
  int wave = tid >> 6, lane = tid & 63;
  if (lane == 0) { red[wave] = s1; red[wave + 4] = s2; }
  __syncthreads();
  float S1 = red[0] + red[1] + red[2] + red[3];
  float S2 = red[4] + red[5] + red[6] + red[7];
  float mu = S1 * (1.f / NDIM);
  float var = S2 * (1.f / NDIM) - mu * mu;
  float inv = rsqrtf(var + 1e-3f);
  float4 gm = reinterpret_cast<const float4*>(gamma)[tid];
  float4 bt = reinterpret_cast<const float4*>(beta)[tid];
  float4 o;
  o.x = (v0 - mu) * inv * gm.x + bt.x;
  o.y = (v1 - mu) * inv * gm.y + bt.y;
  o.z = (v2 - mu) * inv * gm.z + bt.z;
  o.w = (v3 - mu) * inv * gm.w + bt.w;
  reinterpret_cast<float4*>(Out + (size_t)blockIdx.x * NDIM)[tid] = o;
}

extern "C" void kernel_launch(void* const* d_in, const int* in_sizes, int n_in,
                              void* d_out, int out_size, void* d_ws, size_t ws_size,
                              hipStream_t stream) {
  const float* inp = (const float*)d_in[0];
  const float* w1 = (const float*)d_in[1];
  const float* b1 = (const float*)d_in[2];
  const float* w2 = (const float*)d_in[3];
  const float* b2 = (const float*)d_in[4];
  const float* wg = (const float*)d_in[5];
  const float* bg = (const float*)d_in[6];
  const float* wsk = (const float*)d_in[7];
  const float* bs = (const float*)d_in[8];
  const float* gamma = (const float*)d_in[9];
  const float* beta = (const float*)d_in[10];

  char* p = (char*)d_ws;
  const size_t act_bf16 = (size_t)M_TOT * NDIM * 2;
  const size_t w_bf16 = (size_t)NDIM * NDIM * 2;
  unsigned short* Ain = (unsigned short*)p; p += act_bf16;
  unsigned short* H   = (unsigned short*)p; p += act_bf16;
  unsigned short* G   = (unsigned short*)p; p += act_bf16;
  unsigned short* S   = (unsigned short*)p; p += act_bf16;
  unsigned short* Ybf = (unsigned short*)p; p += act_bf16;
  unsigned short* W1t = (unsigned short*)p; p += w_bf16;
  unsigned short* W2t = (unsigned short*)p; p += w_bf16;
  unsigned short* Wgt = (unsigned short*)p; p += w_bf16;
  unsigned short* Wst = (unsigned short*)p; p += w_bf16;

  cast_in<<<(M_TOT * NDIM / 4 + 255) / 256, 256, 0, stream>>>(inp, Ain, M_TOT * NDIM / 4);
  dim3 tg(32, 32);
  tcast<<<tg, 256, 0, stream>>>(w1, W1t);
  tcast<<<tg, 256, 0, stream>>>(w2, W2t);
  tcast<<<tg, 256, 0, stream>>>(wg, Wgt);
  tcast<<<tg, 256, 0, stream>>>(wsk, Wst);

  trigemm<<<(M_TOT / 128) * (NDIM / 128), 256, 0, stream>>>(
      Ain, W1t, Wgt, Wst, b1, bg, bs, H, G, S);
  gemm_y<<<(M_TOT / 256) * (NDIM / 256), 512, 0, stream>>>(H, W2t, b2, Ybf, G, S);
  layernorm_bf<<<M_TOT, 256, 0, stream>>>(Ybf, (float*)d_out, gamma, beta);
}